// Round 2
// baseline (180.300 us; speedup 1.0000x reference)
//
#include <hip/hip_runtime.h>
#include <math.h>

#define B 8
#define C 64
#define HIN 224
#define WIN 224
#define PLANE (HIN*WIN)        // 50176
#define PLANE4 (PLANE/4)       // 12544
#define QUART (PLANE4/4)       // 3136
#define OH 64
#define OW 128
#define OUT_PER_BC (OH*OW)     // 8192
#define NGRID (OH*OW)
#define POOLED_SIZE (B*C*OH*OW) // 4194304

// ws layout (floats):
// [0, 2048)            : partial sums [bc][quarter]
// [4096, 4096+131072)  : coords [b][8192] float2 (ix, iy)
#define WS_PARTIAL 0
#define WS_COORDS 4096

#define PI_F 3.14159265358979323846f

__device__ __forceinline__ float bilinear(const float* __restrict__ p,
                                          float ix, float iy) {
    float x0f = floorf(ix), y0f = floorf(iy);
    int x0 = (int)x0f, y0 = (int)y0f;
    float wx = ix - x0f, wy = iy - y0f;
    int x1 = min(x0 + 1, WIN - 1);
    int y1 = min(y0 + 1, HIN - 1);
    const float* r0 = p + y0 * WIN;
    const float* r1 = p + y1 * WIN;
    float v00 = r0[x0], v01 = r0[x1], v10 = r1[x0], v11 = r1[x1];
    float v0 = v00 + (v01 - v00) * wx;
    float v1 = v10 + (v11 - v10) * wx;
    return v0 + (v1 - v0) * wy;
}

// -------- K1: GAP partial sums + constant-region fill (fused) --------
// grid = bc*4 + q  (2048 blocks)
__global__ __launch_bounds__(256) void k1_gap_fill(const float* __restrict__ x,
                                                   const float* __restrict__ l_t,
                                                   float* __restrict__ ws,
                                                   float* __restrict__ out) {
    int blk = blockIdx.x;
    int bc  = blk >> 2, q = blk & 3;
    const float* plane = x + (size_t)bc * PLANE;
    const float4* p = (const float4*)plane + q * QUART;
    int tid = threadIdx.x;
    float s = 0.f;
#pragma unroll
    for (int k = 0; k < 12; ++k) {
        float4 v = p[tid + k * 256];
        s += (v.x + v.y) + (v.z + v.w);
    }
    if (tid < QUART - 12 * 256) {
        float4 v = p[tid + 12 * 256];
        s += (v.x + v.y) + (v.z + v.w);
    }

    // Constant region of out[bc]: grid == (0,0)+l_t outside the 64x128 corner,
    // so after 4x4 pooling every output with h>=16 || w>=32 equals ONE bilinear
    // sample. 1920 float4 stores split across the 4 quarter-blocks (480 each).
    {
        int b = bc >> 6;
        float gx = l_t[2 * b], gy = l_t[2 * b + 1];
        float ixc = fminf(fmaxf(((gx + 1.f) * (float)WIN - 1.f) * 0.5f, 0.f), (float)(WIN - 1));
        float iyc = fminf(fmaxf(((gy + 1.f) * (float)HIN - 1.f) * 0.5f, 0.f), (float)(HIN - 1));
        float vc = bilinear(plane, ixc, iyc);
        float4 v4 = make_float4(vc, vc, vc, vc);
        float4* o4 = (float4*)(out + (size_t)bc * OUT_PER_BC);
        int end = q * 480 + 480;
        for (int it = q * 480 + tid; it < end; it += 256) {
            int off;
            if (it < 384) {                 // rows 0..15, cols 32..127 (24 float4/row)
                int r = it / 24;
                off = r * 32 + 8 + (it - r * 24);
            } else {                        // rows 16..63, full (32 float4/row)
                int t2 = it - 384;
                off = (16 + (t2 >> 5)) * 32 + (t2 & 31);
            }
            o4[off] = v4;
        }
    }

    for (int off = 32; off; off >>= 1) s += __shfl_down(s, off, 64);
    __shared__ float lds[4];
    if ((tid & 63) == 0) lds[tid >> 6] = s;
    __syncthreads();
    if (tid == 0) ws[WS_PARTIAL + blk] = lds[0] + lds[1] + lds[2] + lds[3];
}

// -------- K2: MLP (redundant per block) + coord table --------
// 256 blocks x 256 threads; block handles 256 grid points of one batch b.
__global__ __launch_bounds__(256) void k2_coords(const float* __restrict__ w1,
                                                 const float* __restrict__ b1,
                                                 const float* __restrict__ w2,
                                                 const float* __restrict__ b2,
                                                 const float* __restrict__ l_t,
                                                 float* __restrict__ ws,
                                                 float* __restrict__ out_weight) {
    __shared__ float branch[B * C];    // 512
    __shared__ float hidden[256];      // 8 x 32
    __shared__ float wv[16];
    int tid = threadIdx.x;
    for (int i = tid; i < B * C; i += 256) {
        const float* pp = ws + WS_PARTIAL + i * 4;
        branch[i] = (pp[0] + pp[1] + pp[2] + pp[3]) * (1.0f / PLANE);
    }
    __syncthreads();
    {
        int bb = tid >> 5, m = tid & 31;
        float h = b1[m];
#pragma unroll 8
        for (int c = 0; c < C; ++c) h += branch[bb * C + c] * w1[c * 32 + m];
        hidden[tid] = fmaxf(h, 0.f);
    }
    __syncthreads();
    if (tid < 16) {
        int bb = tid >> 1, k = tid & 1;
        float s = b2[k];
#pragma unroll
        for (int m = 0; m < 32; ++m) s += hidden[bb * 32 + m] * w2[m * 2 + k];
        float v = 1.f / (1.f + expf(-s));
        wv[tid] = v;
        if (blockIdx.x == 0) out_weight[tid] = v;
    }
    __syncthreads();

    int p = blockIdx.x * 256 + tid;    // [0, 65536)
    int b = p >> 13;
    int rem = p & 8191;
    int i = rem >> 7;
    int j = rem & 127;
    float lo = logf(wv[b * 2 + 0] * 0.01f);
    float hi = logf(wv[b * 2 + 1] * 0.6f);
    float xg = (float)(i - 32) * (1.f / 32.f);
    float yg = (float)(j - 64) * (1.f / 64.f);
    float rr = sqrtf(xg * xg + yg * yg);
    float logr = logf(fmaxf(rr, 1e-12f));
    float r = 64.f * (logr - lo) / (hi - lo);
    float a = atan2f(yg, xg);
    if (!(a > 0.f)) a = 2.f * PI_F + a;
    float t = 0.5f * a * 64.f / PI_F;
    float gx = t * (1.f / 32.f) - 1.f + l_t[b * 2 + 0];
    float gy = r * (1.f / 32.f) - 1.f + l_t[b * 2 + 1];
    float ix = ((gx + 1.f) * (float)WIN - 1.f) * 0.5f;
    float iy = ((gy + 1.f) * (float)HIN - 1.f) * 0.5f;
    ix = fminf(fmaxf(ix, 0.f), (float)(WIN - 1));
    iy = fminf(fmaxf(iy, 0.f), (float)(HIN - 1));
    ((float2*)(ws + WS_COORDS))[p] = make_float2(ix, iy);
}

// -------- K3: corner only — one thread per pooled output --------
// 262144 outputs -> 1024 blocks x 256 threads
__global__ __launch_bounds__(256) void k3_corner(const float* __restrict__ x,
                                                 const float2* __restrict__ coords,
                                                 float* __restrict__ out) {
    int o = blockIdx.x * 256 + threadIdx.x;   // [0, 262144)
    int b = o >> 15;
    int c = (o >> 9) & 63;
    int h = (o >> 5) & 15;
    int w = o & 31;
    const float* plane = x + (size_t)((b << 6) | c) * PLANE;
    const float2* cb = coords + ((size_t)b << 13);
    float acc = 0.f;
#pragma unroll
    for (int di = 0; di < 4; ++di) {
        const float4* cr = (const float4*)(cb + ((4 * h + di) << 7) + (w << 2));
        float4 q0 = cr[0];
        float4 q1 = cr[1];
        acc += bilinear(plane, q0.x, q0.y);
        acc += bilinear(plane, q0.z, q0.w);
        acc += bilinear(plane, q1.x, q1.y);
        acc += bilinear(plane, q1.z, q1.w);
    }
    out[((size_t)((b << 6) | c) << 13) + (h << 7) + w] = acc * (1.f / 16.f);
}

extern "C" void kernel_launch(void* const* d_in, const int* in_sizes, int n_in,
                              void* d_out, int out_size, void* d_ws, size_t ws_size,
                              hipStream_t stream) {
    const float* x   = (const float*)d_in[0];
    const float* l_t = (const float*)d_in[1];
    const float* w1  = (const float*)d_in[2];
    const float* b1  = (const float*)d_in[3];
    const float* w2  = (const float*)d_in[4];
    const float* b2  = (const float*)d_in[5];
    float* out = (float*)d_out;
    float* ws  = (float*)d_ws;

    k1_gap_fill<<<dim3(B * C * 4), dim3(256), 0, stream>>>(x, l_t, ws, out);
    k2_coords<<<dim3(256), dim3(256), 0, stream>>>(w1, b1, w2, b2, l_t, ws,
                                                   out + POOLED_SIZE);
    k3_corner<<<dim3(1024), dim3(256), 0, stream>>>(x, (const float2*)(ws + WS_COORDS), out);
}